// Round 7
// baseline (937.015 us; speedup 1.0000x reference)
//
#include <hip/hip_runtime.h>

typedef unsigned long long u64;
typedef unsigned short u16;
typedef unsigned int u32;

// ---------------------------------------------------------------------------
// HierarchicalLFQHVQVAE forward — R7.
// - 12 dispatches (was 17): single prep_all; enc1 splits f32 x in-kernel
//   (no cast_x round-trip); finalize fused into recon (atomic counter).
// - Activations in split bf16 planes [hi|lo]; projections = bf16 MFMA over
//   K'=3K (A'=[ah|al|ah] wrap x B'=[wh|wh|wl]).
// - dist stage-1: 128x128 bf16 MFMA + XCD swizzle, u32 keys, best-2/block.
// - Stage-2: top-8 exact f32 re-rank + gather + commit + idx.
// ---------------------------------------------------------------------------

namespace {

__device__ __forceinline__ float gelu_f(float x) {
  return 0.5f * x * (1.0f + erff(x * 0.70710678118654752440f));
}
__device__ __forceinline__ float sigmoid_f(float x) {
  return 1.0f / (1.0f + expf(-x));
}
__device__ __forceinline__ u64 pack_key(float d, unsigned j) {
  unsigned u = __float_as_uint(d);
  u = (u & 0x80000000u) ? ~u : (u | 0x80000000u);
  return ((u64)u << 32) | j;
}
__device__ __forceinline__ u16 bf16_rne(float x) {
  unsigned u = __float_as_uint(x);
  unsigned r = (u + 0x7FFFu + ((u >> 16) & 1u)) >> 16;
  return (u16)r;
}
__device__ __forceinline__ float bf16_to_f(u16 h) {
  return __uint_as_float((unsigned)h << 16);
}
__device__ __forceinline__ u64 min64(u64 a, u64 b) { return a < b ? a : b; }

__device__ __forceinline__ void load_lds16(const void* g, void* l) {
  __builtin_amdgcn_global_load_lds(
      (const __attribute__((address_space(1))) void*)g,
      (__attribute__((address_space(3))) void*)l, 16, 0, 0);
}

typedef short bf16x8 __attribute__((ext_vector_type(8)));
typedef float f32x4 __attribute__((ext_vector_type(4)));

// ===========================================================================
// prep_all: one launch for every weight/codebook transform + sums zeroing.
// block ranges:
//  [0,1024)    zcb: f64 norms + bf16 cast (4 rows/block)
//  [1024,1536) qcb: same
//  [1536,1792) zW : Lipschitz norm + split3 (1 row/block, K=512)
//  [1792,1920) qW : same (K=256)
//  [1920,2048) eW1 split3 (64x512)
//  [2048,2176) eW2 split3 (512x64)
//  [2176,2208) dW1 cast
//  [2208,2336) dW2 cast
//  [2336,3360) oW cast
// ===========================================================================
__global__ void prep_all(
    const float* __restrict__ zcb, u16* __restrict__ zcbh,
    float* __restrict__ zcbn, const float* __restrict__ qcb,
    u16* __restrict__ qcbh, float* __restrict__ qcbn,
    const float* __restrict__ zW, const float* __restrict__ zci,
    u16* __restrict__ zWns, const float* __restrict__ qW,
    const float* __restrict__ qci, u16* __restrict__ qWns,
    const float* __restrict__ eW1, u16* __restrict__ eW1s,
    const float* __restrict__ eW2, u16* __restrict__ eW2s,
    const float* __restrict__ dW1, u16* __restrict__ dW1b,
    const float* __restrict__ dW2, u16* __restrict__ dW2b,
    const float* __restrict__ oW, u16* __restrict__ oWb,
    float* __restrict__ sums) {
  const int b = blockIdx.x;
  const int tid = threadIdx.x;
  if (b == 0 && tid < 8) ((u32*)sums)[tid] = 0;  // sums[0..2] + counter

  if (b < 1536) {  // codebooks: norms (f64) + bf16 cast
    const float* cb;
    u16* cbh;
    float* cbn;
    int K, bb = b;
    if (bb < 1024) { cb = zcb; cbh = zcbh; cbn = zcbn; K = 256; }
    else { bb -= 1024; cb = qcb; cbh = qcbh; cbn = qcbn; K = 128; }
    const int row = bb * 4 + (tid >> 6);
    const int lane = tid & 63;
    double s = 0.0;
    for (int k = lane; k < K; k += 64) {
      const float v = cb[(size_t)row * K + k];
      cbh[(size_t)row * K + k] = bf16_rne(v);
      s += (double)v * (double)v;
    }
#pragma unroll
    for (int o = 32; o > 0; o >>= 1) s += __shfl_down(s, o);
    if (lane == 0) cbn[row] = (float)s;
  } else if (b < 1920) {  // Lipschitz norm + split3
    const float* W;
    const float* ci;
    u16* D;
    int K, row;
    if (b < 1792) { W = zW; ci = zci; D = zWns; K = 512; row = b - 1536; }
    else { W = qW; ci = qci; D = qWns; K = 256; row = b - 1792; }
    float s = 0.f;
    for (int k = tid; k < K; k += 256) s += fabsf(W[(size_t)row * K + k]);
#pragma unroll
    for (int o = 32; o > 0; o >>= 1) s += __shfl_down(s, o);
    __shared__ float p[4];
    if ((tid & 63) == 0) p[tid >> 6] = s;
    __syncthreads();
    const float tot = p[0] + p[1] + p[2] + p[3];
    const float c = ci[row];
    const float sp = (c > 20.f) ? c : log1pf(expf(c));
    const float scale = fminf(1.f, sp / tot);
    for (int k = tid; k < K; k += 256) {
      const float v = W[(size_t)row * K + k] * scale;
      const u16 h = bf16_rne(v);
      const u16 l = bf16_rne(v - bf16_to_f(h));
      D[(size_t)row * 3 * K + k] = h;
      D[(size_t)row * 3 * K + K + k] = h;
      D[(size_t)row * 3 * K + 2 * K + k] = l;
    }
  } else if (b < 2048) {  // eW1 split3, 64x512
    const int i = (b - 1920) * 256 + tid;
    const int r = i >> 9, k = i & 511;
    const float v = eW1[i];
    const u16 h = bf16_rne(v);
    const u16 l = bf16_rne(v - bf16_to_f(h));
    eW1s[(size_t)r * 1536 + k] = h;
    eW1s[(size_t)r * 1536 + 512 + k] = h;
    eW1s[(size_t)r * 1536 + 1024 + k] = l;
  } else if (b < 2176) {  // eW2 split3, 512x64
    const int i = (b - 2048) * 256 + tid;
    const int r = i >> 6, k = i & 63;
    const float v = eW2[i];
    const u16 h = bf16_rne(v);
    const u16 l = bf16_rne(v - bf16_to_f(h));
    eW2s[(size_t)r * 192 + k] = h;
    eW2s[(size_t)r * 192 + 64 + k] = h;
    eW2s[(size_t)r * 192 + 128 + k] = l;
  } else if (b < 2208) {
    const int i = (b - 2176) * 256 + tid;
    dW1b[i] = bf16_rne(dW1[i]);
  } else if (b < 2336) {
    const int i = (b - 2208) * 256 + tid;
    dW2b[i] = bf16_rne(dW2[i]);
  } else {
    const int i = (b - 2336) * 256 + tid;
    oWb[i] = bf16_rne(oW[i]);
  }
}

// ===========================================================================
// enc1: A = x f32 [32768][512], split to (hi,lo) bf16 in-kernel (LDS planes);
// B = eW1s planes [wh|wh|wl] (use planes 0 and 2). 3-term MFMA.
// TM=128, TN=64, 128 threads (2 waves). Output h1s split, stride 128.
// ===========================================================================
__global__ __launch_bounds__(128) void enc1_kernel(
    const float* __restrict__ A, const u16* __restrict__ B3,
    const float* __restrict__ bias, u16* __restrict__ C) {
  __shared__ __align__(16) u16 Ah[128 * 64];
  __shared__ __align__(16) u16 Al[128 * 64];
  __shared__ __align__(16) u16 Bh[64 * 64];
  __shared__ __align__(16) u16 Bl[64 * 64];
  const int tid = threadIdx.x;
  const int lane = tid & 63, w = tid >> 6;
  const int quad = lane >> 4, l15 = lane & 15;
  const int waveM = w * 64;
  const int rowBase = blockIdx.y * 128;

  f32x4 acc[4][4] = {};

  for (int k0 = 0; k0 < 512; k0 += 64) {
    __syncthreads();
    // B staging (DMA): 64 rows x 8 chunks
#pragma unroll
    for (int i = 0; i < 4; ++i) {
      const int ch = i * 128 + tid;
      const int r = ch >> 3, c = ch & 7, g = c ^ (r & 7);
      const size_t rb = (size_t)r * 1536 + k0 + g * 8;
      load_lds16(B3 + rb, (char*)Bh + ch * 16);
      load_lds16(B3 + rb + 1024, (char*)Bl + ch * 16);
    }
    // A staging: f32 load -> split -> ds_write (128 rows x 16 float4)
#pragma unroll
    for (int i = 0; i < 16; ++i) {
      const int ch = i * 128 + tid;
      const int r = ch >> 4, c4 = ch & 15;
      const float4 v =
          *(const float4*)(A + (size_t)(rowBase + r) * 512 + k0 + c4 * 4);
      const float vv[4] = {v.x, v.y, v.z, v.w};
      u16 hv[4], lv[4];
#pragma unroll
      for (int j = 0; j < 4; ++j) {
        hv[j] = bf16_rne(vv[j]);
        lv[j] = bf16_rne(vv[j] - bf16_to_f(hv[j]));
      }
      const int g = (c4 >> 1) ^ (r & 7);
      const int off = r * 64 + g * 8 + (c4 & 1) * 4;
      *(ushort4*)(Ah + off) = make_ushort4(hv[0], hv[1], hv[2], hv[3]);
      *(ushort4*)(Al + off) = make_ushort4(lv[0], lv[1], lv[2], lv[3]);
    }
    __syncthreads();
#pragma unroll
    for (int ks = 0; ks < 2; ++ks) {
      bf16x8 ahf[4], alf[4], bhf[4], blf[4];
      const int ch = ks * 4 + quad;
#pragma unroll
      for (int mi = 0; mi < 4; ++mi) {
        const int rl = waveM + mi * 16 + l15;
        const int so = rl * 64 + (ch ^ (rl & 7)) * 8;
        ahf[mi] = *(const bf16x8*)(Ah + so);
        alf[mi] = *(const bf16x8*)(Al + so);
      }
#pragma unroll
      for (int ni = 0; ni < 4; ++ni) {
        const int rl = ni * 16 + l15;
        const int so = rl * 64 + (ch ^ (rl & 7)) * 8;
        bhf[ni] = *(const bf16x8*)(Bh + so);
        blf[ni] = *(const bf16x8*)(Bl + so);
      }
#pragma unroll
      for (int mi = 0; mi < 4; ++mi)
#pragma unroll
        for (int ni = 0; ni < 4; ++ni) {
          acc[mi][ni] = __builtin_amdgcn_mfma_f32_16x16x32_bf16(
              ahf[mi], bhf[ni], acc[mi][ni], 0, 0, 0);
          acc[mi][ni] = __builtin_amdgcn_mfma_f32_16x16x32_bf16(
              alf[mi], bhf[ni], acc[mi][ni], 0, 0, 0);
          acc[mi][ni] = __builtin_amdgcn_mfma_f32_16x16x32_bf16(
              ahf[mi], blf[ni], acc[mi][ni], 0, 0, 0);
        }
    }
  }

#pragma unroll
  for (int mi = 0; mi < 4; ++mi)
#pragma unroll
    for (int r = 0; r < 4; ++r) {
      const int row = rowBase + waveM + mi * 16 + quad * 4 + r;
#pragma unroll
      for (int ni = 0; ni < 4; ++ni) {
        const int col = ni * 16 + l15;
        const float v = gelu_f(acc[mi][ni][r] + bias[col]);
        const u16 h = bf16_rne(v);
        const u16 l = bf16_rne(v - bf16_to_f(h));
        C[(size_t)row * 128 + col] = h;
        C[(size_t)row * 128 + 64 + col] = l;
      }
    }
}

// ===========================================================================
// Unified MFMA GEMM. Modes: GELU_SPLIT / SIG_SPLIT / GELU_B16 / RECON.
// RECON: f32 store + MSE atomicAdd + last-block finalize (writes out[0..5]).
// ===========================================================================
enum { U_GELU_SPLIT = 0, U_SIG_SPLIT = 1, U_GELU_B16 = 2, U_RECON = 3 };

template <int TM, int TN, int NW, int MODE>
__global__ __launch_bounds__(NW * 64) void gemm_uni(
    const u16* __restrict__ A, const u16* __restrict__ B,
    const float* __restrict__ bias, void* __restrict__ Cv,
    const float* __restrict__ X, float* __restrict__ sums,
    float* __restrict__ outfin, int Ktot, int wrapA, int strideA, int N) {
  __shared__ __align__(16) u16 As[TM * 64];
  __shared__ __align__(16) u16 Bs[TN * 64];
  constexpr int NT = NW * 64;
  constexpr int AIT = (TM * 8) / NT;
  constexpr int BIT = (TN * 8) / NT;
  const int tid = threadIdx.x;
  const int lane = tid & 63, w = tid >> 6;
  const int quad = lane >> 4, l15 = lane & 15;
  const int waveM = (TN == 64) ? w * 64 : (w & 1) * 64;
  const int waveN = (TN == 64) ? 0 : (w >> 1) * 64;
  const int rowBase = blockIdx.y * TM;
  const int colBase = blockIdx.x * TN;

  f32x4 acc[4][4] = {};

  for (int k0 = 0; k0 < Ktot; k0 += 64) {
    const int sk0 = (k0 >= wrapA) ? k0 - wrapA : k0;
    __syncthreads();
#pragma unroll
    for (int i = 0; i < AIT; ++i) {
      const int ch = i * NT + tid;
      const int r = ch >> 3, c = ch & 7, g = c ^ (r & 7);
      load_lds16(A + (size_t)(rowBase + r) * strideA + sk0 + g * 8,
                 (char*)As + ch * 16);
    }
#pragma unroll
    for (int i = 0; i < BIT; ++i) {
      const int ch = i * NT + tid;
      const int r = ch >> 3, c = ch & 7, g = c ^ (r & 7);
      load_lds16(B + (size_t)(colBase + r) * Ktot + k0 + g * 8,
                 (char*)Bs + ch * 16);
    }
    __syncthreads();
#pragma unroll
    for (int ks = 0; ks < 2; ++ks) {
      bf16x8 af[4], bf[4];
      const int ch = ks * 4 + quad;
#pragma unroll
      for (int mi = 0; mi < 4; ++mi) {
        const int rl = waveM + mi * 16 + l15;
        af[mi] = *(const bf16x8*)(As + rl * 64 + (ch ^ (rl & 7)) * 8);
      }
#pragma unroll
      for (int ni = 0; ni < 4; ++ni) {
        const int rl = waveN + ni * 16 + l15;
        bf[ni] = *(const bf16x8*)(Bs + rl * 64 + (ch ^ (rl & 7)) * 8);
      }
#pragma unroll
      for (int mi = 0; mi < 4; ++mi)
#pragma unroll
        for (int ni = 0; ni < 4; ++ni)
          acc[mi][ni] = __builtin_amdgcn_mfma_f32_16x16x32_bf16(
              af[mi], bf[ni], acc[mi][ni], 0, 0, 0);
    }
  }

  if constexpr (MODE == U_GELU_SPLIT || MODE == U_SIG_SPLIT) {
    u16* S = (u16*)Cv;
#pragma unroll
    for (int mi = 0; mi < 4; ++mi)
#pragma unroll
      for (int r = 0; r < 4; ++r) {
        const int row = rowBase + waveM + mi * 16 + quad * 4 + r;
#pragma unroll
        for (int ni = 0; ni < 4; ++ni) {
          const int col = colBase + waveN + ni * 16 + l15;
          const float pre = acc[mi][ni][r] + bias[col];
          const float v = (MODE == U_GELU_SPLIT) ? gelu_f(pre) : sigmoid_f(pre);
          const u16 h = bf16_rne(v);
          const u16 l = bf16_rne(v - bf16_to_f(h));
          S[(size_t)row * 2 * N + col] = h;
          S[(size_t)row * 2 * N + N + col] = l;
        }
      }
  } else if constexpr (MODE == U_GELU_B16) {
    u16* C = (u16*)Cv;
#pragma unroll
    for (int mi = 0; mi < 4; ++mi)
#pragma unroll
      for (int r = 0; r < 4; ++r) {
        const int row = rowBase + waveM + mi * 16 + quad * 4 + r;
#pragma unroll
        for (int ni = 0; ni < 4; ++ni) {
          const int col = colBase + waveN + ni * 16 + l15;
          C[(size_t)row * N + col] =
              bf16_rne(gelu_f(acc[mi][ni][r] + bias[col]));
        }
      }
  } else {  // U_RECON (+ fused finalize)
    float* C = (float*)Cv;
    float local = 0.f;
#pragma unroll
    for (int mi = 0; mi < 4; ++mi)
#pragma unroll
      for (int r = 0; r < 4; ++r) {
        const int row = rowBase + waveM + mi * 16 + quad * 4 + r;
#pragma unroll
        for (int ni = 0; ni < 4; ++ni) {
          const int col = colBase + waveN + ni * 16 + l15;
          const float val = acc[mi][ni][r] + bias[col];
          const float d = val - X[(size_t)row * N + col];
          local += d * d;
          C[(size_t)row * N + col] = val;
        }
      }
#pragma unroll
    for (int o = 32; o > 0; o >>= 1) local += __shfl_down(local, o);
    __shared__ float psum[NW];
    if (lane == 0) psum[w] = local;
    __syncthreads();
    if (tid == 0) {
      float t = 0.f;
#pragma unroll
      for (int i = 0; i < NW; ++i) t += psum[i];
      atomicAdd(&sums[2], t);
      __threadfence();
      u32* cnt = (u32*)&sums[4];
      const u32 old = atomicAdd(cnt, 1u);
      if (old == gridDim.x * gridDim.y - 1) {
        const float s2 = atomicAdd(&sums[2], 0.0f);  // coherent read
        const float cz = sums[0] / (32768.0f * 256.0f);
        const float cq = sums[1] / (32768.0f * 128.0f);
        const float rec = s2 / (32768.0f * 512.0f);
        outfin[0] = rec + 0.5f * cz + 0.5f * cq;
        outfin[1] = rec;
        outfin[2] = cz;
        outfin[3] = cz;
        outfin[4] = cq;
        outfin[5] = cq;
      }
    }
  }
}

// ===========================================================================
// Stage-1 distance: 128 codes x 128 batch + XCD swizzle (gridDim.y == 256).
// ===========================================================================
__global__ __launch_bounds__(256) void dist2_kernel(
    const u16* __restrict__ CB, const u16* __restrict__ ZB,
    const float* __restrict__ cbn, u32* __restrict__ cand, int Ktot,
    int strideB, int nx) {
  __shared__ __align__(16) u16 As[128 * 64];
  __shared__ __align__(16) u16 Bs[128 * 64];
  __shared__ u32 wred[128][2][2];
  const int tid = threadIdx.x;
  const int lane = tid & 63, w = tid >> 6;
  const int quad = lane >> 4, l15 = lane & 15;
  const int waveM = (w & 1) * 64;   // codes
  const int waveN = (w >> 1) * 64;  // batch
  const int lin = blockIdx.y * gridDim.x + blockIdx.x;
  const int xcd = lin & 7;
  const int slot = lin >> 3;
  const int bt = xcd * 32 + (slot & 31);
  const int ct = slot >> 5;
  const int codeBase = ct * 128;
  const int rowBase = bt * 128;

  f32x4 acc[4][4] = {};

  for (int k0 = 0; k0 < Ktot; k0 += 64) {
    __syncthreads();
#pragma unroll
    for (int i = 0; i < 4; ++i) {
      const int ch = i * 256 + tid;
      const int r = ch >> 3, c = ch & 7, g = c ^ (r & 7);
      load_lds16(CB + (size_t)(codeBase + r) * Ktot + k0 + g * 8,
                 (char*)As + ch * 16);
      load_lds16(ZB + (size_t)(rowBase + r) * strideB + k0 + g * 8,
                 (char*)Bs + ch * 16);
    }
    __syncthreads();
#pragma unroll
    for (int ks = 0; ks < 2; ++ks) {
      bf16x8 af[4], bf[4];
      const int ch = ks * 4 + quad;
#pragma unroll
      for (int mi = 0; mi < 4; ++mi) {
        const int rl = waveM + mi * 16 + l15;
        af[mi] = *(const bf16x8*)(As + rl * 64 + (ch ^ (rl & 7)) * 8);
      }
#pragma unroll
      for (int ni = 0; ni < 4; ++ni) {
        const int rl = waveN + ni * 16 + l15;
        bf[ni] = *(const bf16x8*)(Bs + rl * 64 + (ch ^ (rl & 7)) * 8);
      }
#pragma unroll
      for (int mi = 0; mi < 4; ++mi)
#pragma unroll
        for (int ni = 0; ni < 4; ++ni)
          acc[mi][ni] = __builtin_amdgcn_mfma_f32_16x16x32_bf16(
              af[mi], bf[ni], acc[mi][ni], 0, 0, 0);
    }
  }

  float cnf[4][4];
  unsigned codeL[4][4];
#pragma unroll
  for (int mi = 0; mi < 4; ++mi)
#pragma unroll
    for (int r = 0; r < 4; ++r) {
      const unsigned code = codeBase + waveM + mi * 16 + quad * 4 + r;
      codeL[mi][r] = code;
      cnf[mi][r] = cbn[code] * 512.0f + 131072.0f;
    }
#pragma unroll
  for (int ni = 0; ni < 4; ++ni) {
    u32 b0 = ~0u, b1 = ~0u;
#pragma unroll
    for (int mi = 0; mi < 4; ++mi)
#pragma unroll
      for (int r = 0; r < 4; ++r) {
        const float kf = fmaf(acc[mi][ni][r], -1024.0f, cnf[mi][r]);
        u32 iv = (u32)kf;
        iv = iv > 0xFFFFFu ? 0xFFFFFu : iv;
        const u32 key = (iv << 12) | codeL[mi][r];
        if (key < b0) { b1 = b0; b0 = key; }
        else if (key < b1) { b1 = key; }
      }
#pragma unroll
    for (int off = 16; off < 64; off <<= 1) {
      const u32 o0 = __shfl_xor(b0, off);
      const u32 o1 = __shfl_xor(b1, off);
      const u32 n0 = min(b0, o0);
      const u32 n1 = min(max(b0, o0), min(b1, o1));
      b0 = n0; b1 = n1;
    }
    if (quad == 0) {
      wred[waveN + ni * 16 + l15][w & 1][0] = b0;
      wred[waveN + ni * 16 + l15][w & 1][1] = b1;
    }
  }
  __syncthreads();
  if (tid < 128) {
    const u32 a0 = wred[tid][0][0], a1 = wred[tid][0][1];
    const u32 c0 = wred[tid][1][0], c1 = wred[tid][1][1];
    const u32 b0 = min(a0, c0);
    const u32 b1 = min(max(a0, c0), min(a1, c1));
    u32* dst = cand + (size_t)(rowBase + tid) * (2 * nx) + 2 * ct;
    *(u64*)dst = ((u64)b1 << 32) | b0;
  }
}

// ===========================================================================
// Stage-2 rerank (unchanged): top-8 exact f32 re-rank + gather/commit/idx.
// ===========================================================================
template <int K, int NC, int LEVEL>
__global__ __launch_bounds__(256) void rerank_kernel(
    const u32* __restrict__ cand, const u16* __restrict__ zes,
    const float* __restrict__ cb, const float* __restrict__ cbn,
    float* __restrict__ outq, u16* __restrict__ wsq,
    float* __restrict__ out_idx, float* __restrict__ sumptr) {
  const int w = threadIdx.x >> 6, lane = threadIdx.x & 63;
  const int row = blockIdx.x * 4 + w;

  u32 key = (lane < NC) ? cand[(size_t)row * NC + lane] : ~0u;
  unsigned topcode[8];
#pragma unroll
  for (int t = 0; t < 8; ++t) {
    u32 m = key;
#pragma unroll
    for (int off = 1; off < 64; off <<= 1) m = min(m, __shfl_xor(m, off));
    topcode[t] = m & 0xFFFu;
    if (key == m) key = ~0u;
  }

  const int g = lane >> 3, sub = lane & 7;
  unsigned ci = topcode[0];
#pragma unroll
  for (int t = 1; t < 8; ++t) ci = (g == t) ? topcode[t] : ci;

  const u16* zr = zes + (size_t)row * 2 * K;
  const float* cr = cb + (size_t)ci * K;
  float dot = 0.f;
#pragma unroll
  for (int k = sub * (K / 8); k < (sub + 1) * (K / 8); k += 4) {
    const ushort4 hv = *(const ushort4*)(zr + k);
    const ushort4 lv = *(const ushort4*)(zr + K + k);
    const float4 cv = *(const float4*)(cr + k);
    dot = fmaf(bf16_to_f(hv.x) + bf16_to_f(lv.x), cv.x, dot);
    dot = fmaf(bf16_to_f(hv.y) + bf16_to_f(lv.y), cv.y, dot);
    dot = fmaf(bf16_to_f(hv.z) + bf16_to_f(lv.z), cv.z, dot);
    dot = fmaf(bf16_to_f(hv.w) + bf16_to_f(lv.w), cv.w, dot);
  }
#pragma unroll
  for (int off = 1; off < 8; off <<= 1) dot += __shfl_xor(dot, off);
  u64 k2 = pack_key(cbn[ci] - 2.0f * dot, ci);
#pragma unroll
  for (int off = 8; off < 64; off <<= 1) k2 = min64(k2, __shfl_xor(k2, off));
  const unsigned best = (unsigned)k2;
  if (lane == 0) out_idx[row] = (float)best;

  const float* br = cb + (size_t)best * K;
  float local = 0.f;
  for (int c = lane; c < K; c += 64) {
    const float v = br[c];
    const float z = bf16_to_f(zr[c]) + bf16_to_f(zr[K + c]);
    const float d = z - v;
    local += d * d;
    outq[(size_t)row * K + c] = v;
    if (LEVEL == 0) {
      const u16 h = bf16_rne(v);
      wsq[(size_t)row * 2 * K + c] = h;
      wsq[(size_t)row * 2 * K + K + c] = bf16_rne(v - bf16_to_f(h));
    } else {
      wsq[(size_t)row * K + c] = bf16_rne(v);
    }
  }
#pragma unroll
  for (int o = 32; o > 0; o >>= 1) local += __shfl_down(local, o);
  __shared__ float p[4];
  if (lane == 0) p[w] = local;
  __syncthreads();
  if (threadIdx.x == 0) atomicAdd(sumptr, p[0] + p[1] + p[2] + p[3]);
}

}  // namespace

extern "C" void kernel_launch(void* const* d_in, const int* in_sizes, int n_in,
                              void* d_out, int out_size, void* d_ws,
                              size_t ws_size, hipStream_t stream) {
  const float* x   = (const float*)d_in[0];
  const float* eW1 = (const float*)d_in[1];
  const float* eb1 = (const float*)d_in[2];
  const float* eW2 = (const float*)d_in[3];
  const float* eb2 = (const float*)d_in[4];
  const float* zW  = (const float*)d_in[5];
  const float* zb  = (const float*)d_in[6];
  const float* zci = (const float*)d_in[7];
  const float* zcb = (const float*)d_in[8];
  const float* qW  = (const float*)d_in[9];
  const float* qb  = (const float*)d_in[10];
  const float* qci = (const float*)d_in[11];
  const float* qcb = (const float*)d_in[12];
  const float* dW1 = (const float*)d_in[13];
  const float* db1 = (const float*)d_in[14];
  const float* dW2 = (const float*)d_in[15];
  const float* db2 = (const float*)d_in[16];
  const float* oW  = (const float*)d_in[17];
  const float* ob  = (const float*)d_in[18];

  float* out = (float*)d_out;
  float* out_xr = out + 6;
  float* out_zq = out_xr + (size_t)32768 * 512;
  float* out_qq = out_zq + (size_t)32768 * 256;
  float* out_zi = out_qq + (size_t)32768 * 128;
  float* out_qi = out_zi + 32768;

  // ---- workspace layout ---------------------------------------------------
  char* wsb = (char*)d_ws;
  u16*  zWns = (u16*) (wsb + 0x0000000);  // 256 x 1536  768K
  u16*  qWns = (u16*) (wsb + 0x00C0000);  // 128 x 768   192K
  u16*  eW1s = (u16*) (wsb + 0x00F0000);  // 64 x 1536   192K
  u16*  eW2s = (u16*) (wsb + 0x0120000);  // 512 x 192   192K
  u16*  dW1b = (u16*) (wsb + 0x0150000);  // 64x128       16K
  u16*  dW2b = (u16*) (wsb + 0x0154000);  // 512x64       64K
  u16*  oWb  = (u16*) (wsb + 0x0164000);  // 512x512     512K
  u16*  zcbh = (u16*) (wsb + 0x01E4000);  // 4096x256      2M
  u16*  qcbh = (u16*) (wsb + 0x03E4000);  // 2048x128    512K
  float* zcbn = (float*)(wsb + 0x0464000); // 16K
  float* qcbn = (float*)(wsb + 0x0468000); // 8K
  float* sums = (float*)(wsb + 0x046A000); // sums[0..2] + counter @ [4]
  // time-windowed regions:
  u16*  h1s  = (u16*) (wsb + 0x0480000);  // 8M  [enc1 -> enc2]
  u16*  h1b  = (u16*) (wsb + 0x0480000);  //   4M [dec1 -> dec2]
  u16*  zes  = (u16*) (wsb + 0x0C80000);  // 32M [zproj -> zdist,zrerank]
  u16*  qes  = (u16*) (wsb + 0x0C80000);  //   16M [qproj -> qdist,qrerank]
  u16*  hb   = (u16*) (wsb + 0x0C80000);  //   32M [dec2 -> recon]
  u16*  hs   = (u16*) (wsb + 0x2C80000);  // 64M [enc2 -> zproj]
  u32*  candz = (u32*)(wsb + 0x2C80000);  //   8M [zdist -> zrerank]
  u16*  zqs  = (u16*) (wsb + 0x3480000);  //   32M [zrerank -> qproj]
  u32*  candq = (u32*)(wsb + 0x2C80000);  //   4M [qdist -> qrerank]
  u16*  qqb  = (u16*) (wsb + 0x5480000);  //   8M [qrerank -> dec1]

  // ---- prep (1 launch; also zeroes sums + finalize counter) ----
  prep_all<<<3360, 256, 0, stream>>>(zcb, zcbh, zcbn, qcb, qcbh, qcbn, zW, zci,
                                     zWns, qW, qci, qWns, eW1, eW1s, eW2, eW2s,
                                     dW1, dW1b, dW2, dW2b, oW, oWb, sums);

  // ---- encoder ----
  enc1_kernel<<<dim3(1, 256), 128, 0, stream>>>(x, eW1s, eb1, h1s);
  gemm_uni<128, 128, 4, U_GELU_SPLIT><<<dim3(4, 256), 256, 0, stream>>>(
      h1s, eW2s, eb2, hs, nullptr, nullptr, nullptr, 192, 128, 128, 512);
  gemm_uni<128, 128, 4, U_SIG_SPLIT><<<dim3(2, 256), 256, 0, stream>>>(
      hs, zWns, zb, zes, nullptr, nullptr, nullptr, 1536, 1024, 1024, 256);

  // ---- z quantize ----
  dist2_kernel<<<dim3(32, 256), 256, 0, stream>>>(zcbh, zes, zcbn, candz,
                                                  256, 512, 32);
  rerank_kernel<256, 64, 0><<<8192, 256, 0, stream>>>(
      candz, zes, zcb, zcbn, out_zq, zqs, out_zi, &sums[0]);

  // ---- q level ----
  gemm_uni<128, 128, 4, U_SIG_SPLIT><<<dim3(1, 256), 256, 0, stream>>>(
      zqs, qWns, qb, qes, nullptr, nullptr, nullptr, 768, 512, 512, 128);
  dist2_kernel<<<dim3(16, 256), 256, 0, stream>>>(qcbh, qes, qcbn, candq,
                                                  128, 256, 16);
  rerank_kernel<128, 32, 1><<<8192, 256, 0, stream>>>(
      candq, qes, qcb, qcbn, out_qq, qqb, out_qi, &sums[1]);

  // ---- decoder ----
  gemm_uni<128, 64, 2, U_GELU_B16><<<dim3(1, 256), 128, 0, stream>>>(
      qqb, dW1b, db1, h1b, nullptr, nullptr, nullptr, 128, 1 << 30, 128, 64);
  gemm_uni<128, 128, 4, U_GELU_B16><<<dim3(4, 256), 256, 0, stream>>>(
      h1b, dW2b, db2, hb, nullptr, nullptr, nullptr, 64, 1 << 30, 64, 512);
  gemm_uni<128, 128, 4, U_RECON><<<dim3(4, 256), 256, 0, stream>>>(
      hb, oWb, ob, out_xr, x, sums, out, 512, 1 << 30, 512, 512);

  (void)in_sizes; (void)n_in; (void)out_size; (void)ws_size;
}

// Round 8
// 836.828 us; speedup vs baseline: 1.1197x; 1.1197x over previous
//
#include <hip/hip_runtime.h>

typedef unsigned long long u64;
typedef unsigned short u16;
typedef unsigned int u32;

// ---------------------------------------------------------------------------
// HierarchicalLFQHVQVAE forward — R8.
// Base = R6 (855 us) with dist2 replaced by a persistent-codebook kernel:
// - block owns one 128-code tile; its MFMA A-fragments are hoisted into
//   registers once (full K), then a single 64KB LDS buffer cycles through
//   BTG batch tiles (stage -> MFMA -> best-2 epilogue). Staged bytes ~halve,
//   LDS reads per MFMA halve, barriers drop to 4/tile.
// - grid mapped so lin%8 == batch-window id -> per-XCD L2 working set
//   (2MB batch + 2MB codebook) fits the 4MB L2.
// Everything else identical to R6 (R7's fusions regressed and are reverted).
// ---------------------------------------------------------------------------

namespace {

constexpr int kBatch = 32768;

__device__ __forceinline__ float gelu_f(float x) {
  return 0.5f * x * (1.0f + erff(x * 0.70710678118654752440f));
}
__device__ __forceinline__ float sigmoid_f(float x) {
  return 1.0f / (1.0f + expf(-x));
}
__device__ __forceinline__ u64 pack_key(float d, unsigned j) {
  unsigned u = __float_as_uint(d);
  u = (u & 0x80000000u) ? ~u : (u | 0x80000000u);
  return ((u64)u << 32) | j;
}
__device__ __forceinline__ u16 bf16_rne(float x) {
  unsigned u = __float_as_uint(x);
  unsigned r = (u + 0x7FFFu + ((u >> 16) & 1u)) >> 16;
  return (u16)r;
}
__device__ __forceinline__ float bf16_to_f(u16 h) {
  return __uint_as_float((unsigned)h << 16);
}
__device__ __forceinline__ u64 min64(u64 a, u64 b) { return a < b ? a : b; }

__device__ __forceinline__ void load_lds16(const void* g, void* l) {
  __builtin_amdgcn_global_load_lds(
      (const __attribute__((address_space(1))) void*)g,
      (__attribute__((address_space(3))) void*)l, 16, 0, 0);
}

typedef short bf16x8 __attribute__((ext_vector_type(8)));
typedef float f32x4 __attribute__((ext_vector_type(4)));

// ===========================================================================
// Prep (3 kernels) — identical to R6
// ===========================================================================
__global__ void prep_cb_kernel(const float* __restrict__ zcb,
                               u16* __restrict__ zcbh, float* __restrict__ zcbn,
                               const float* __restrict__ qcb,
                               u16* __restrict__ qcbh, float* __restrict__ qcbn) {
  int b = blockIdx.x;
  const float* cb;
  u16* cbh;
  float* cbn;
  int K;
  if (b < 1024) { cb = zcb; cbh = zcbh; cbn = zcbn; K = 256; }
  else { b -= 1024; cb = qcb; cbh = qcbh; cbn = qcbn; K = 128; }
  const int row = b * 4 + (threadIdx.x >> 6);
  const int lane = threadIdx.x & 63;
  double s = 0.0;
  for (int k = lane; k < K; k += 64) {
    const float v = cb[(size_t)row * K + k];
    cbh[(size_t)row * K + k] = bf16_rne(v);
    s += (double)v * (double)v;
  }
#pragma unroll
  for (int o = 32; o > 0; o >>= 1) s += __shfl_down(s, o);
  if (lane == 0) cbn[row] = (float)s;
}

__global__ void prep_w_kernel(
    const float* __restrict__ zW, const float* __restrict__ zci,
    const float* __restrict__ qW, const float* __restrict__ qci,
    const float* __restrict__ eW1, const float* __restrict__ eW2,
    u16* __restrict__ zWns, u16* __restrict__ qWns, u16* __restrict__ eW1s,
    u16* __restrict__ eW2s, const float* __restrict__ dW1,
    const float* __restrict__ dW2, const float* __restrict__ oW,
    u16* __restrict__ dW1b, u16* __restrict__ dW2b, u16* __restrict__ oWb) {
  const int b = blockIdx.x;
  const int tid = threadIdx.x;
  if (b < 384) {
    const float* W;
    const float* ci;
    u16* D;
    int K, row;
    if (b < 256) { W = zW; ci = zci; D = zWns; K = 512; row = b; }
    else { W = qW; ci = qci; D = qWns; K = 256; row = b - 256; }
    float s = 0.f;
    for (int k = tid; k < K; k += 256) s += fabsf(W[(size_t)row * K + k]);
#pragma unroll
    for (int o = 32; o > 0; o >>= 1) s += __shfl_down(s, o);
    __shared__ float p[4];
    if ((tid & 63) == 0) p[tid >> 6] = s;
    __syncthreads();
    const float tot = p[0] + p[1] + p[2] + p[3];
    const float c = ci[row];
    const float sp = (c > 20.f) ? c : log1pf(expf(c));
    const float scale = fminf(1.f, sp / tot);
    for (int k = tid; k < K; k += 256) {
      const float v = W[(size_t)row * K + k] * scale;
      const u16 h = bf16_rne(v);
      const u16 l = bf16_rne(v - bf16_to_f(h));
      D[(size_t)row * 3 * K + k] = h;
      D[(size_t)row * 3 * K + K + k] = h;
      D[(size_t)row * 3 * K + 2 * K + k] = l;
    }
  } else if (b < 512) {  // eW1 split3, 64x512
    const int i = (b - 384) * 256 + tid;
    const int r = i >> 9, k = i & 511;
    const float v = eW1[i];
    const u16 h = bf16_rne(v);
    const u16 l = bf16_rne(v - bf16_to_f(h));
    eW1s[(size_t)r * 1536 + k] = h;
    eW1s[(size_t)r * 1536 + 512 + k] = h;
    eW1s[(size_t)r * 1536 + 1024 + k] = l;
  } else if (b < 640) {  // eW2 split3, 512x64
    const int i = (b - 512) * 256 + tid;
    const int r = i >> 6, k = i & 63;
    const float v = eW2[i];
    const u16 h = bf16_rne(v);
    const u16 l = bf16_rne(v - bf16_to_f(h));
    eW2s[(size_t)r * 192 + k] = h;
    eW2s[(size_t)r * 192 + 64 + k] = h;
    eW2s[(size_t)r * 192 + 128 + k] = l;
  } else if (b < 672) {
    const int i = (b - 640) * 256 + tid;
    dW1b[i] = bf16_rne(dW1[i]);
  } else if (b < 800) {
    const int i = (b - 672) * 256 + tid;
    dW2b[i] = bf16_rne(dW2[i]);
  } else {
    const int i = (b - 800) * 256 + tid;
    oWb[i] = bf16_rne(oW[i]);
  }
}

__global__ void cast_split_x_kernel(const float* __restrict__ x,
                                    u16* __restrict__ xs) {
  const int i = blockIdx.x * 256 + threadIdx.x;
  const int row = i >> 7, c4 = i & 127;
  const float4 v = *(const float4*)(x + (size_t)row * 512 + c4 * 4);
  const float vv[4] = {v.x, v.y, v.z, v.w};
  u16 hv[4], lv[4];
#pragma unroll
  for (int j = 0; j < 4; ++j) {
    hv[j] = bf16_rne(vv[j]);
    lv[j] = bf16_rne(vv[j] - bf16_to_f(hv[j]));
  }
  *(ushort4*)(xs + (size_t)row * 1024 + c4 * 4) =
      make_ushort4(hv[0], hv[1], hv[2], hv[3]);
  *(ushort4*)(xs + (size_t)row * 1024 + 512 + c4 * 4) =
      make_ushort4(lv[0], lv[1], lv[2], lv[3]);
}

// ===========================================================================
// Unified MFMA GEMM (identical to R6).
// ===========================================================================
enum { U_GELU_SPLIT = 0, U_SIG_SPLIT = 1, U_GELU_B16 = 2, U_RECON = 3 };

template <int TM, int TN, int NW, int MODE>
__global__ __launch_bounds__(NW * 64) void gemm_uni(
    const u16* __restrict__ A, const u16* __restrict__ B,
    const float* __restrict__ bias, void* __restrict__ Cv,
    const float* __restrict__ X, float* __restrict__ sumptr, int Ktot,
    int wrapA, int strideA, int N) {
  __shared__ __align__(16) u16 As[TM * 64];
  __shared__ __align__(16) u16 Bs[TN * 64];
  constexpr int NT = NW * 64;
  constexpr int AIT = (TM * 8) / NT;
  constexpr int BIT = (TN * 8) / NT;
  const int tid = threadIdx.x;
  const int lane = tid & 63, w = tid >> 6;
  const int quad = lane >> 4, l15 = lane & 15;
  const int waveM = (TN == 64) ? w * 64 : (w & 1) * 64;
  const int waveN = (TN == 64) ? 0 : (w >> 1) * 64;
  const int rowBase = blockIdx.y * TM;
  const int colBase = blockIdx.x * TN;

  f32x4 acc[4][4] = {};

  for (int k0 = 0; k0 < Ktot; k0 += 64) {
    const int sk0 = (k0 >= wrapA) ? k0 - wrapA : k0;
    __syncthreads();
#pragma unroll
    for (int i = 0; i < AIT; ++i) {
      const int ch = i * NT + tid;
      const int r = ch >> 3, c = ch & 7, g = c ^ (r & 7);
      load_lds16(A + (size_t)(rowBase + r) * strideA + sk0 + g * 8,
                 (char*)As + ch * 16);
    }
#pragma unroll
    for (int i = 0; i < BIT; ++i) {
      const int ch = i * NT + tid;
      const int r = ch >> 3, c = ch & 7, g = c ^ (r & 7);
      load_lds16(B + (size_t)(colBase + r) * Ktot + k0 + g * 8,
                 (char*)Bs + ch * 16);
    }
    __syncthreads();
#pragma unroll
    for (int ks = 0; ks < 2; ++ks) {
      bf16x8 af[4], bf[4];
      const int ch = ks * 4 + quad;
#pragma unroll
      for (int mi = 0; mi < 4; ++mi) {
        const int rl = waveM + mi * 16 + l15;
        af[mi] = *(const bf16x8*)(As + rl * 64 + (ch ^ (rl & 7)) * 8);
      }
#pragma unroll
      for (int ni = 0; ni < 4; ++ni) {
        const int rl = waveN + ni * 16 + l15;
        bf[ni] = *(const bf16x8*)(Bs + rl * 64 + (ch ^ (rl & 7)) * 8);
      }
#pragma unroll
      for (int mi = 0; mi < 4; ++mi)
#pragma unroll
        for (int ni = 0; ni < 4; ++ni)
          acc[mi][ni] = __builtin_amdgcn_mfma_f32_16x16x32_bf16(
              af[mi], bf[ni], acc[mi][ni], 0, 0, 0);
    }
  }

  if constexpr (MODE == U_GELU_SPLIT || MODE == U_SIG_SPLIT) {
    u16* S = (u16*)Cv;
#pragma unroll
    for (int mi = 0; mi < 4; ++mi)
#pragma unroll
      for (int r = 0; r < 4; ++r) {
        const int row = rowBase + waveM + mi * 16 + quad * 4 + r;
#pragma unroll
        for (int ni = 0; ni < 4; ++ni) {
          const int col = colBase + waveN + ni * 16 + l15;
          const float pre = acc[mi][ni][r] + bias[col];
          const float v = (MODE == U_GELU_SPLIT) ? gelu_f(pre) : sigmoid_f(pre);
          const u16 h = bf16_rne(v);
          const u16 l = bf16_rne(v - bf16_to_f(h));
          S[(size_t)row * 2 * N + col] = h;
          S[(size_t)row * 2 * N + N + col] = l;
        }
      }
  } else if constexpr (MODE == U_GELU_B16) {
    u16* C = (u16*)Cv;
#pragma unroll
    for (int mi = 0; mi < 4; ++mi)
#pragma unroll
      for (int r = 0; r < 4; ++r) {
        const int row = rowBase + waveM + mi * 16 + quad * 4 + r;
#pragma unroll
        for (int ni = 0; ni < 4; ++ni) {
          const int col = colBase + waveN + ni * 16 + l15;
          C[(size_t)row * N + col] =
              bf16_rne(gelu_f(acc[mi][ni][r] + bias[col]));
        }
      }
  } else {  // U_RECON
    float* C = (float*)Cv;
    float local = 0.f;
#pragma unroll
    for (int mi = 0; mi < 4; ++mi)
#pragma unroll
      for (int r = 0; r < 4; ++r) {
        const int row = rowBase + waveM + mi * 16 + quad * 4 + r;
#pragma unroll
        for (int ni = 0; ni < 4; ++ni) {
          const int col = colBase + waveN + ni * 16 + l15;
          const float val = acc[mi][ni][r] + bias[col];
          const float d = val - X[(size_t)row * N + col];
          local += d * d;
          C[(size_t)row * N + col] = val;
        }
      }
#pragma unroll
    for (int o = 32; o > 0; o >>= 1) local += __shfl_down(local, o);
    __shared__ float psum[NW];
    if (lane == 0) psum[w] = local;
    __syncthreads();
    if (tid == 0) {
      float t = 0.f;
#pragma unroll
      for (int i = 0; i < NW; ++i) t += psum[i];
      atomicAdd(sumptr, t);
    }
  }
}

// ===========================================================================
// Persistent-codebook stage-1 distance.
// Block = one 128-code tile (ct = blockIdx.y) x one batch window
// (btg = blockIdx.x, BTG tiles of 128 rows). Codebook tile staged into the
// single 64KB(z)/32KB(q) LDS buffer once, its MFMA fragments hoisted to
// registers (full K), then the buffer is recycled per batch tile.
// wred aliases the buffer (dead between compute-end and next staging).
// XCD note: lin%8 == btg(%8) -> per-XCD L2 set = batch window + codebook.
// ===========================================================================
template <int KT, int BTG, int MINW>
__global__ __launch_bounds__(256, MINW) void dist2p_kernel(
    const u16* __restrict__ CB, const u16* __restrict__ ZB,
    const float* __restrict__ cbn, u32* __restrict__ cand, int strideB,
    int nx) {
  constexpr int CH = KT / 8;       // 16B chunks per row
  constexpr int KSTEPS = KT / 32;  // MFMA k-steps
  __shared__ __align__(16) u16 buf[128 * KT];
  u32* wred = (u32*)buf;  // [128][2][2], aliased (buf dead at epilogue)
  const int tid = threadIdx.x;
  const int lane = tid & 63, w = tid >> 6;
  const int quad = lane >> 4, l15 = lane & 15;
  const int waveM = (w & 1) * 64;   // code half
  const int waveN = (w >> 1) * 64;  // batch half
  const int ct = blockIdx.y;
  const int btg = blockIdx.x;
  const int codeBase = ct * 128;

  // ---- stage codebook tile (full K), hoist all A fragments ----
#pragma unroll
  for (int i = 0; i < (128 * CH) / 256; ++i) {
    const int ch = i * 256 + tid;
    const int r = ch / CH, c = ch % CH, g = c ^ (r & 7);
    load_lds16(CB + (size_t)(codeBase + r) * KT + g * 8, (char*)buf + ch * 16);
  }
  __syncthreads();
  bf16x8 af[KSTEPS][4];
#pragma unroll
  for (int kk = 0; kk < KSTEPS; ++kk)
#pragma unroll
    for (int mi = 0; mi < 4; ++mi) {
      const int rl = waveM + mi * 16 + l15;
      const int sw = (kk * 4 + quad) ^ (rl & 7);
      af[kk][mi] = *(const bf16x8*)(buf + rl * KT + sw * 8);
    }
  float cnf[4][4];
#pragma unroll
  for (int mi = 0; mi < 4; ++mi)
#pragma unroll
    for (int r = 0; r < 4; ++r)
      cnf[mi][r] =
          cbn[codeBase + waveM + mi * 16 + quad * 4 + r] * 512.0f + 131072.0f;

  for (int bt = 0; bt < BTG; ++bt) {
    const int rowBase = (btg * BTG + bt) * 128;
    __syncthreads();  // af reads (it 0) / prev merge reads done
#pragma unroll
    for (int i = 0; i < (128 * CH) / 256; ++i) {
      const int ch = i * 256 + tid;
      const int r = ch / CH, c = ch % CH, g = c ^ (r & 7);
      load_lds16(ZB + (size_t)(rowBase + r) * strideB + g * 8,
                 (char*)buf + ch * 16);
    }
    __syncthreads();  // Bs visible

    f32x4 acc[4][4] = {};
#pragma unroll
    for (int kk = 0; kk < KSTEPS; ++kk) {
      bf16x8 bf[4];
#pragma unroll
      for (int ni = 0; ni < 4; ++ni) {
        const int rn = waveN + ni * 16 + l15;
        const int sw = (kk * 4 + quad) ^ (rn & 7);
        bf[ni] = *(const bf16x8*)(buf + rn * KT + sw * 8);
      }
#pragma unroll
      for (int mi = 0; mi < 4; ++mi)
#pragma unroll
        for (int ni = 0; ni < 4; ++ni)
          acc[mi][ni] = __builtin_amdgcn_mfma_f32_16x16x32_bf16(
              af[kk][mi], bf[ni], acc[mi][ni], 0, 0, 0);
    }
    __syncthreads();  // all bf reads done -> buf (wred) reusable

#pragma unroll
    for (int ni = 0; ni < 4; ++ni) {
      u32 b0 = ~0u, b1 = ~0u;
#pragma unroll
      for (int mi = 0; mi < 4; ++mi)
#pragma unroll
        for (int r = 0; r < 4; ++r) {
          const float kf = fmaf(acc[mi][ni][r], -1024.0f, cnf[mi][r]);
          u32 iv = (u32)kf;
          iv = iv > 0xFFFFFu ? 0xFFFFFu : iv;
          const u32 key =
              (iv << 12) | (codeBase + waveM + mi * 16 + quad * 4 + r);
          if (key < b0) { b1 = b0; b0 = key; }
          else if (key < b1) { b1 = key; }
        }
#pragma unroll
      for (int off = 16; off < 64; off <<= 1) {
        const u32 o0 = __shfl_xor(b0, off);
        const u32 o1 = __shfl_xor(b1, off);
        const u32 n0 = min(b0, o0);
        const u32 n1 = min(max(b0, o0), min(b1, o1));
        b0 = n0; b1 = n1;
      }
      if (quad == 0) {
        const int rloc = waveN + ni * 16 + l15;
        wred[rloc * 4 + (w & 1) * 2 + 0] = b0;
        wred[rloc * 4 + (w & 1) * 2 + 1] = b1;
      }
    }
    __syncthreads();  // wred visible
    if (tid < 128) {
      const u32 a0 = wred[tid * 4 + 0], a1 = wred[tid * 4 + 1];
      const u32 c0 = wred[tid * 4 + 2], c1 = wred[tid * 4 + 3];
      const u32 b0 = min(a0, c0);
      const u32 b1 = min(max(a0, c0), min(a1, c1));
      u32* dst = cand + (size_t)(rowBase + tid) * (2 * nx) + 2 * ct;
      *(u64*)dst = ((u64)b1 << 32) | b0;
    }
  }
}

// ===========================================================================
// Stage-2 rerank (identical to R6).
// ===========================================================================
template <int K, int NC, int LEVEL>
__global__ __launch_bounds__(256) void rerank_kernel(
    const u32* __restrict__ cand, const u16* __restrict__ zes,
    const float* __restrict__ cb, const float* __restrict__ cbn,
    float* __restrict__ outq, u16* __restrict__ wsq,
    float* __restrict__ out_idx, float* __restrict__ sumptr) {
  const int w = threadIdx.x >> 6, lane = threadIdx.x & 63;
  const int row = blockIdx.x * 4 + w;

  u32 key = (lane < NC) ? cand[(size_t)row * NC + lane] : ~0u;
  unsigned topcode[8];
#pragma unroll
  for (int t = 0; t < 8; ++t) {
    u32 m = key;
#pragma unroll
    for (int off = 1; off < 64; off <<= 1) m = min(m, __shfl_xor(m, off));
    topcode[t] = m & 0xFFFu;
    if (key == m) key = ~0u;
  }

  const int g = lane >> 3, sub = lane & 7;
  unsigned ci = topcode[0];
#pragma unroll
  for (int t = 1; t < 8; ++t) ci = (g == t) ? topcode[t] : ci;

  const u16* zr = zes + (size_t)row * 2 * K;
  const float* cr = cb + (size_t)ci * K;
  float dot = 0.f;
#pragma unroll
  for (int k = sub * (K / 8); k < (sub + 1) * (K / 8); k += 4) {
    const ushort4 hv = *(const ushort4*)(zr + k);
    const ushort4 lv = *(const ushort4*)(zr + K + k);
    const float4 cv = *(const float4*)(cr + k);
    dot = fmaf(bf16_to_f(hv.x) + bf16_to_f(lv.x), cv.x, dot);
    dot = fmaf(bf16_to_f(hv.y) + bf16_to_f(lv.y), cv.y, dot);
    dot = fmaf(bf16_to_f(hv.z) + bf16_to_f(lv.z), cv.z, dot);
    dot = fmaf(bf16_to_f(hv.w) + bf16_to_f(lv.w), cv.w, dot);
  }
#pragma unroll
  for (int off = 1; off < 8; off <<= 1) dot += __shfl_xor(dot, off);
  u64 k2 = pack_key(cbn[ci] - 2.0f * dot, ci);
#pragma unroll
  for (int off = 8; off < 64; off <<= 1) k2 = min64(k2, __shfl_xor(k2, off));
  const unsigned best = (unsigned)k2;
  if (lane == 0) out_idx[row] = (float)best;

  const float* br = cb + (size_t)best * K;
  float local = 0.f;
  for (int c = lane; c < K; c += 64) {
    const float v = br[c];
    const float z = bf16_to_f(zr[c]) + bf16_to_f(zr[K + c]);
    const float d = z - v;
    local += d * d;
    outq[(size_t)row * K + c] = v;
    if (LEVEL == 0) {
      const u16 h = bf16_rne(v);
      wsq[(size_t)row * 2 * K + c] = h;
      wsq[(size_t)row * 2 * K + K + c] = bf16_rne(v - bf16_to_f(h));
    } else {
      wsq[(size_t)row * K + c] = bf16_rne(v);
    }
  }
#pragma unroll
  for (int o = 32; o > 0; o >>= 1) local += __shfl_down(local, o);
  __shared__ float p[4];
  if (lane == 0) p[w] = local;
  __syncthreads();
  if (threadIdx.x == 0) atomicAdd(sumptr, p[0] + p[1] + p[2] + p[3]);
}

__global__ void finalize_kernel(const float* __restrict__ sums,
                                float* __restrict__ out) {
  const float cz = sums[0] / ((float)kBatch * 256.f);
  const float cq = sums[1] / ((float)kBatch * 128.f);
  const float rec = sums[2] / ((float)kBatch * 512.f);
  out[0] = rec + 0.5f * cz + 0.5f * cq;
  out[1] = rec;
  out[2] = cz;
  out[3] = cz;
  out[4] = cq;
  out[5] = cq;
}

}  // namespace

extern "C" void kernel_launch(void* const* d_in, const int* in_sizes, int n_in,
                              void* d_out, int out_size, void* d_ws,
                              size_t ws_size, hipStream_t stream) {
  const float* x   = (const float*)d_in[0];
  const float* eW1 = (const float*)d_in[1];
  const float* eb1 = (const float*)d_in[2];
  const float* eW2 = (const float*)d_in[3];
  const float* eb2 = (const float*)d_in[4];
  const float* zW  = (const float*)d_in[5];
  const float* zb  = (const float*)d_in[6];
  const float* zci = (const float*)d_in[7];
  const float* zcb = (const float*)d_in[8];
  const float* qW  = (const float*)d_in[9];
  const float* qb  = (const float*)d_in[10];
  const float* qci = (const float*)d_in[11];
  const float* qcb = (const float*)d_in[12];
  const float* dW1 = (const float*)d_in[13];
  const float* db1 = (const float*)d_in[14];
  const float* dW2 = (const float*)d_in[15];
  const float* db2 = (const float*)d_in[16];
  const float* oW  = (const float*)d_in[17];
  const float* ob  = (const float*)d_in[18];

  float* out = (float*)d_out;
  float* out_xr = out + 6;
  float* out_zq = out_xr + (size_t)32768 * 512;
  float* out_qq = out_zq + (size_t)32768 * 256;
  float* out_zi = out_qq + (size_t)32768 * 128;
  float* out_qi = out_zi + 32768;

  // ---- workspace layout (identical to R6) ---------------------------------
  char* wsb = (char*)d_ws;
  u16*  zWns = (u16*) (wsb + 0x0000000);  // 256 x 1536  768K
  u16*  qWns = (u16*) (wsb + 0x00C0000);  // 128 x 768   192K
  u16*  eW1s = (u16*) (wsb + 0x00F0000);  // 64 x 1536   192K
  u16*  eW2s = (u16*) (wsb + 0x0120000);  // 512 x 192   192K
  u16*  dW1b = (u16*) (wsb + 0x0150000);  // 64x128       16K
  u16*  dW2b = (u16*) (wsb + 0x0154000);  // 512x64       64K
  u16*  oWb  = (u16*) (wsb + 0x0164000);  // 512x512     512K
  u16*  zcbh = (u16*) (wsb + 0x01E4000);  // 4096x256      2M
  u16*  qcbh = (u16*) (wsb + 0x03E4000);  // 2048x128    512K
  float* zcbn = (float*)(wsb + 0x0464000); // 16K
  float* qcbn = (float*)(wsb + 0x0468000); // 8K
  float* sums = (float*)(wsb + 0x046A000); // 3 floats
  // time-windowed regions:
  u16*  h1s  = (u16*) (wsb + 0x0480000);  // 8M  [enc1 -> enc2]
  u16*  h1b  = (u16*) (wsb + 0x0480000);  //   4M [dec1 -> dec2]
  u16*  zes  = (u16*) (wsb + 0x0C80000);  // 32M [zproj -> zdist,zrerank]
  u16*  qes  = (u16*) (wsb + 0x0C80000);  //   16M [qproj -> qdist,qrerank]
  u16*  hb   = (u16*) (wsb + 0x0C80000);  //   32M [dec2 -> recon]
  u16*  xs   = (u16*) (wsb + 0x2C80000);  // 64M [cast -> enc1]
  u16*  hs   = (u16*) (wsb + 0x2C80000);  //   64M [enc2 -> zproj]
  u32*  candz = (u32*)(wsb + 0x2C80000);  //   8M [zdist -> zrerank]
  u16*  zqs  = (u16*) (wsb + 0x3480000);  //   32M [zrerank -> qproj]
  u32*  candq = (u32*)(wsb + 0x2C80000);  //   4M [qdist -> qrerank]
  u16*  qqb  = (u16*) (wsb + 0x5480000);  //   8M [qrerank -> dec1]

  hipMemsetAsync(sums, 0, 3 * sizeof(float), stream);

  // ---- prep (3 launches) ----
  prep_cb_kernel<<<1536, 256, 0, stream>>>(zcb, zcbh, zcbn, qcb, qcbh, qcbn);
  prep_w_kernel<<<1824, 256, 0, stream>>>(zW, zci, qW, qci, eW1, eW2, zWns,
                                          qWns, eW1s, eW2s, dW1, dW2, oW,
                                          dW1b, dW2b, oWb);
  cast_split_x_kernel<<<16384, 256, 0, stream>>>(x, xs);

  // ---- encoder ----
  gemm_uni<128, 64, 2, U_GELU_SPLIT><<<dim3(1, 256), 128, 0, stream>>>(
      xs, eW1s, eb1, h1s, nullptr, nullptr, 1536, 1024, 1024, 64);
  gemm_uni<128, 128, 4, U_GELU_SPLIT><<<dim3(4, 256), 256, 0, stream>>>(
      h1s, eW2s, eb2, hs, nullptr, nullptr, 192, 128, 128, 512);
  gemm_uni<128, 128, 4, U_SIG_SPLIT><<<dim3(2, 256), 256, 0, stream>>>(
      hs, zWns, zb, zes, nullptr, nullptr, 1536, 1024, 1024, 256);

  // ---- z quantize: grid (btg=8, ct=32); lin%8==btg -> XCD-private window
  dist2p_kernel<256, 32, 1><<<dim3(8, 32), 256, 0, stream>>>(
      zcbh, zes, zcbn, candz, 512, 32);
  rerank_kernel<256, 64, 0><<<8192, 256, 0, stream>>>(
      candz, zes, zcb, zcbn, out_zq, zqs, out_zi, &sums[0]);

  // ---- q level ----
  gemm_uni<128, 128, 4, U_SIG_SPLIT><<<dim3(1, 256), 256, 0, stream>>>(
      zqs, qWns, qb, qes, nullptr, nullptr, 768, 512, 512, 128);
  dist2p_kernel<128, 8, 2><<<dim3(32, 16), 256, 0, stream>>>(
      qcbh, qes, qcbn, candq, 256, 16);
  rerank_kernel<128, 32, 1><<<8192, 256, 0, stream>>>(
      candq, qes, qcb, qcbn, out_qq, qqb, out_qi, &sums[1]);

  // ---- decoder ----
  gemm_uni<128, 64, 2, U_GELU_B16><<<dim3(1, 256), 128, 0, stream>>>(
      qqb, dW1b, db1, h1b, nullptr, nullptr, 128, 1 << 30, 128, 64);
  gemm_uni<128, 128, 4, U_GELU_B16><<<dim3(4, 256), 256, 0, stream>>>(
      h1b, dW2b, db2, hb, nullptr, nullptr, 64, 1 << 30, 64, 512);
  gemm_uni<128, 128, 4, U_RECON><<<dim3(4, 256), 256, 0, stream>>>(
      hb, oWb, ob, out_xr, x, &sums[2], 512, 1 << 30, 512, 512);

  finalize_kernel<<<1, 1, 0, stream>>>(sums, out);

  (void)in_sizes; (void)n_in; (void)out_size; (void)ws_size;
}